// Round 4
// baseline (278.356 us; speedup 1.0000x reference)
//
#include <hip/hip_runtime.h>
#include <hip/hip_bf16.h>
#include <stdint.h>

using bf16 = __hip_bfloat16;
typedef __attribute__((ext_vector_type(8))) short short8;
typedef __attribute__((ext_vector_type(4))) float f32x4;

#define BM 128
#define BN 128
#define BK 32

// -------- async global->LDS, 16B per lane (m97 pattern) --------
__device__ __forceinline__ void g2lds16(const void* g, void* l) {
    __builtin_amdgcn_global_load_lds(
        (const __attribute__((address_space(1))) void*)g,
        (__attribute__((address_space(3))) void*)l,
        16, 0, 0);
}

__device__ __forceinline__ short f2bs(float x) {
    union { bf16 h; short s; } u;
    u.h = __float2bfloat16(x);
    return u.s;
}

// -------- fp32 -> bf16 64x64 tile transpose: dst[c][r] = (bf16)src[r][c] ----
__global__ __launch_bounds__(256)
void transpose_cvt(const float* __restrict__ src, ushort* __restrict__ dst,
                   int R, int C, long sstride, long dstride)
{
    __shared__ __align__(16) ushort t[64][72];
    const float* s = src + (size_t)blockIdx.z * sstride;
    ushort*      d = dst + (size_t)blockIdx.z * dstride;
    const int r0 = blockIdx.y * 64, c0 = blockIdx.x * 64;
    const int tid = threadIdx.x;
#pragma unroll
    for (int ii = 0; ii < 4; ++ii) {                 // load f32, cvt, stage
        int idx = ii * 256 + tid;
        int r = idx >> 4, c4 = (idx & 15) * 4;
        float4 v = *(const float4*)&s[(size_t)(r0 + r) * C + c0 + c4];
        union { ushort u[4]; uint2 q; } o;
        o.u[0] = (ushort)f2bs(v.x); o.u[1] = (ushort)f2bs(v.y);
        o.u[2] = (ushort)f2bs(v.z); o.u[3] = (ushort)f2bs(v.w);
        *(uint2*)&t[r][c4] = o.q;
    }
    __syncthreads();
#pragma unroll
    for (int ii = 0; ii < 2; ++ii) {                 // write transposed
        int idx = ii * 256 + tid;
        int c = idx >> 3, r8 = (idx & 7) * 8;
        union { ushort u[8]; uint4 v; } tmp;
#pragma unroll
        for (int j = 0; j < 8; ++j) tmp.u[j] = t[r8 + j][c];
        *(uint4*)&d[(size_t)(c0 + c) * R + r0 + r8] = tmp.v;
    }
}

// -------- fp32 -> bf16 flat convert (4 elems/thread) --------
__global__ __launch_bounds__(256)
void cvt_f32_bf16(const float* __restrict__ in, ushort* __restrict__ out, int n4)
{
    int i = blockIdx.x * 256 + threadIdx.x;
    if (i >= n4) return;
    float4 v = ((const float4*)in)[i];
    union { ushort u[4]; uint2 q; } o;
    o.u[0] = (ushort)f2bs(v.x); o.u[1] = (ushort)f2bs(v.y);
    o.u[2] = (ushort)f2bs(v.z); o.u[3] = (ushort)f2bs(v.w);
    ((uint2*)out)[i] = o.q;
}

// -------- C = A * B^T ; A:[M][K], B:[N][K] row-major, k contiguous --------
// MODE 0: bf16 store. MODE 1: fp32 atomicAdd (split-K). MODE 2: fp32 store.
// A_F32: A operand is fp32 in global memory (staged fp32, cvt at frag load).
template <int MODE, int A_F32>
__global__ __launch_bounds__(256)
void gemm_bt(const void* __restrict__ Av, const bf16* __restrict__ B,
             void* __restrict__ Cv, int M, int N, int K, int kChunks,
             long sA, long sB, long sC)
{
    __shared__ __align__(16) bf16 lA[BM * BK * (A_F32 ? 2 : 1)];
    __shared__ __align__(16) bf16 lB[BN * BK];

    const int z     = blockIdx.z;
    const int batch = z / kChunks;
    const int chunk = z - batch * kChunks;
    const int kLen  = K / kChunks;
    const int k0    = chunk * kLen;

    const int m0 = blockIdx.y * BM;
    const int n0 = blockIdx.x * BN;

    const int tid  = threadIdx.x;
    const int lane = tid & 63;
    const int wave = tid >> 6;
    const int wr   = wave >> 1, wc = wave & 1;   // 2x2 wave grid, 64x64 each
    const int ml   = lane & 15;
    const int q    = lane >> 4;

    // B staging: 512 x 16B, 2 shots
    const int idx0 = tid, idx1 = tid + 256;
    const bf16* Bb = B + (size_t)batch * sB;
    const bf16* b0 = Bb + (size_t)(n0 + (idx0 >> 2)) * K + k0 + (idx0 & 3) * 8;
    const bf16* b1 = Bb + (size_t)(n0 + (idx1 >> 2)) * K + k0 + (idx1 & 3) * 8;

    // A staging pointers
    const float* a32[4];
    const bf16*  a16[2];
    if constexpr (A_F32) {
        const float* Ab = (const float*)Av + (size_t)batch * sA;
#pragma unroll
        for (int s = 0; s < 4; ++s) {
            int idx = s * 256 + tid;
            a32[s] = Ab + (size_t)(m0 + (idx >> 3)) * K + k0 + (idx & 7) * 4;
        }
    } else {
        const bf16* Ab = (const bf16*)Av + (size_t)batch * sA;
        a16[0] = Ab + (size_t)(m0 + (idx0 >> 2)) * K + k0 + (idx0 & 3) * 8;
        a16[1] = Ab + (size_t)(m0 + (idx1 >> 2)) * K + k0 + (idx1 & 3) * 8;
    }

    f32x4 acc[4][4] = {};

    const int nk = kLen / BK;
    for (int kt = 0; kt < nk; ++kt) {
        if constexpr (A_F32) {
            float* lAf = (float*)lA;
#pragma unroll
            for (int s = 0; s < 4; ++s) {
                int idx = s * 256 + tid;
                g2lds16(a32[s], &lAf[idx * 4]);
                a32[s] += BK;
            }
        } else {
            g2lds16(a16[0], &lA[idx0 * 8]);
            g2lds16(a16[1], &lA[idx1 * 8]);
            a16[0] += BK; a16[1] += BK;
        }
        g2lds16(b0, &lB[idx0 * 8]);
        g2lds16(b1, &lB[idx1 * 8]);
        b0 += BK; b1 += BK;
        __syncthreads();

        short8 af[4], bfr[4];
#pragma unroll
        for (int i = 0; i < 4; ++i) {
            if constexpr (A_F32) {
                const float* lAf = (const float*)lA;
                const float* p = &lAf[(wr * 64 + i * 16 + ml) * BK + q * 8];
                float4 x0 = *(const float4*)p;
                float4 x1 = *(const float4*)(p + 4);
                af[i][0] = f2bs(x0.x); af[i][1] = f2bs(x0.y);
                af[i][2] = f2bs(x0.z); af[i][3] = f2bs(x0.w);
                af[i][4] = f2bs(x1.x); af[i][5] = f2bs(x1.y);
                af[i][6] = f2bs(x1.z); af[i][7] = f2bs(x1.w);
            } else {
                af[i] = *(const short8*)&lA[(wr * 64 + i * 16 + ml) * BK + q * 8];
            }
            bfr[i] = *(const short8*)&lB[(wc * 64 + i * 16 + ml) * BK + q * 8];
        }
#pragma unroll
        for (int mi = 0; mi < 4; ++mi)
#pragma unroll
            for (int ni = 0; ni < 4; ++ni)
                acc[mi][ni] = __builtin_amdgcn_mfma_f32_16x16x32_bf16(
                    af[mi], bfr[ni], acc[mi][ni], 0, 0, 0);
        __syncthreads();
    }

    // epilogue: C/D layout col=lane&15, row=(lane>>4)*4+r (m89-verified)
#pragma unroll
    for (int mi = 0; mi < 4; ++mi)
#pragma unroll
        for (int ni = 0; ni < 4; ++ni)
#pragma unroll
            for (int r = 0; r < 4; ++r) {
                int row = m0 + wr * 64 + mi * 16 + q * 4 + r;
                int col = n0 + wc * 64 + ni * 16 + ml;
                if constexpr (MODE == 1) {
                    float* Cf = (float*)Cv + (size_t)batch * sC;
                    atomicAdd(&Cf[(size_t)row * N + col], acc[mi][ni][r]);
                } else if constexpr (MODE == 0) {
                    ushort* Cb = (ushort*)Cv + (size_t)batch * sC;
                    Cb[(size_t)row * N + col] = (ushort)f2bs(acc[mi][ni][r]);
                } else {
                    float* Cf = (float*)Cv + (size_t)batch * sC;
                    Cf[(size_t)row * N + col] = acc[mi][ni][r];
                }
            }
}

// ---------------------------------------------------------------
// fp32 I/O.  O = ((X W^T) X^T) X == X * (W^T (X^T X))   [associative]
//   G  = Xt * Xt^T   (split-K=4, fp32 atomic)     Xt = bf16(X)^T
//   Mt = G * Wt^T    (bf16 store)                 Wt = bf16(W)^T
//   O  = X * Mt^T    (A fp32 on-the-fly cvt, fp32 store)
// d_out (32 MiB) doubles as scratch until step 7 overwrites it:
//   Xt bf16 @0 (16M) | Gf f32 @16M (8M) | G bf16 @24M (4M) | Wt @28M (2M)
// ws: Mt bf16 @0 (4 MiB) — only ws use.
// ---------------------------------------------------------------
extern "C" void kernel_launch(void* const* d_in, const int* in_sizes, int n_in,
                              void* d_out, int out_size, void* d_ws, size_t ws_size,
                              hipStream_t stream)
{
    const int B = 2, N = 4096, D = 1024;
    const float* X = (const float*)d_in[0];   // [B][N][D] fp32
    const float* W = (const float*)d_in[1];   // [D][D]    fp32
    float* out = (float*)d_out;               // [B][N][D] fp32

    char* ob = (char*)d_out;
    ushort* Xt = (ushort*)ob;                  // [B][D][N] bf16, 16 MiB
    float*  Gf = (float*)(ob + (16ll << 20));  // [B][D][D] fp32,  8 MiB
    ushort* G  = (ushort*)(ob + (24ll << 20)); // [B][D][D] bf16,  4 MiB
    ushort* Wt = (ushort*)(ob + (28ll << 20)); // [D][D]    bf16,  2 MiB
    ushort* Mt = (ushort*)d_ws;                // [B][D][D] bf16,  4 MiB

    // 1) Xt[b] = bf16(X[b])^T
    transpose_cvt<<<dim3(D / 64, N / 64, B), 256, 0, stream>>>(
        X, Xt, N, D, (long)N * D, (long)D * N);
    // 2) Wt = bf16(W)^T
    transpose_cvt<<<dim3(D / 64, D / 64, 1), 256, 0, stream>>>(
        W, Wt, D, D, 0, 0);
    // 3) zero split-K accumulator
    (void)hipMemsetAsync(Gf, 0, (size_t)B * D * D * sizeof(float), stream);
    // 4) Gf[b] += Xt[b] * Xt[b]^T   (M=N=D, K=4096, split-K 4)
    gemm_bt<1, 0><<<dim3(D / BN, D / BM, B * 4), 256, 0, stream>>>(
        (const void*)Xt, (const bf16*)Xt, Gf, D, D, N, 4,
        (long)D * N, (long)D * N, (long)D * D);
    // 5) G = bf16(Gf)
    cvt_f32_bf16<<<dim3((B * D * D / 4 + 255) / 256), 256, 0, stream>>>(
        Gf, G, B * D * D / 4);
    // 6) Mt[b] = G[b] * Wt^T   (M=N=K=D)
    gemm_bt<0, 0><<<dim3(D / BN, D / BM, B), 256, 0, stream>>>(
        (const void*)G, (const bf16*)Wt, Mt, D, D, D, 1,
        (long)D * D, 0, (long)D * D);
    // 7) O[b] = X[b] * Mt[b]^T  (M=4096, N=D, K=D; A fp32; overwrites d_out)
    gemm_bt<2, 1><<<dim3(D / BN, N / BM, B), 256, 0, stream>>>(
        (const void*)X, (const bf16*)Mt, out, N, D, D, 1,
        (long)N * D, (long)D * D, (long)N * D);
}

// Round 5
// 205.633 us; speedup vs baseline: 1.3537x; 1.3537x over previous
//
#include <hip/hip_runtime.h>
#include <hip/hip_bf16.h>
#include <stdint.h>

using bf16 = __hip_bfloat16;
typedef __attribute__((ext_vector_type(8))) short short8;
typedef __attribute__((ext_vector_type(4))) float f32x4;

#define BM 128
#define BN 128
#define BK 32

// -------- async global->LDS, 16B per lane (m97 pattern) --------
__device__ __forceinline__ void g2lds16(const void* g, void* l) {
    __builtin_amdgcn_global_load_lds(
        (const __attribute__((address_space(1))) void*)g,
        (__attribute__((address_space(3))) void*)l,
        16, 0, 0);
}

__device__ __forceinline__ short f2bs(float x) {
    union { bf16 h; short s; } u;
    u.h = __float2bfloat16(x);
    return u.s;
}

// ---- LDS XOR swizzles (conflict-free fragment reads; see round-4 notes) ----
// bf16 tile [128][32 bf16] = 4 groups/row of 8 bf16 (16B). swizzle s=(row>>1)&3.
__device__ __forceinline__ int bswz(int row, int cg) { return cg ^ ((row >> 1) & 3); }
// fp32 tile [128][32 f32] = 8 groups/row of 4 f32 (16B). swizzle s=row&7.
__device__ __forceinline__ int fswz(int row, int cg) { return cg ^ (row & 7); }

// -------- fp32 -> bf16 64x64 tile transpose: dst[c][r] = (bf16)src[r][c] ----
__global__ __launch_bounds__(256)
void transpose_cvt(const float* __restrict__ src, ushort* __restrict__ dst,
                   int R, int C, long sstride, long dstride)
{
    __shared__ __align__(16) ushort t[64][72];
    const float* s = src + (size_t)blockIdx.z * sstride;
    ushort*      d = dst + (size_t)blockIdx.z * dstride;
    const int r0 = blockIdx.y * 64, c0 = blockIdx.x * 64;
    const int tid = threadIdx.x;
#pragma unroll
    for (int ii = 0; ii < 4; ++ii) {
        int idx = ii * 256 + tid;
        int r = idx >> 4, c4 = (idx & 15) * 4;
        float4 v = *(const float4*)&s[(size_t)(r0 + r) * C + c0 + c4];
        union { ushort u[4]; uint2 q; } o;
        o.u[0] = (ushort)f2bs(v.x); o.u[1] = (ushort)f2bs(v.y);
        o.u[2] = (ushort)f2bs(v.z); o.u[3] = (ushort)f2bs(v.w);
        *(uint2*)&t[r][c4] = o.q;
    }
    __syncthreads();
#pragma unroll
    for (int ii = 0; ii < 2; ++ii) {
        int idx = ii * 256 + tid;
        int c = idx >> 3, r8 = (idx & 7) * 8;
        union { ushort u[8]; uint4 v; } tmp;
#pragma unroll
        for (int j = 0; j < 8; ++j) tmp.u[j] = t[r8 + j][c];
        *(uint4*)&d[(size_t)(c0 + c) * R + r0 + r8] = tmp.v;
    }
}

// -------- fp32 -> bf16 flat convert (4 elems/thread) --------
__global__ __launch_bounds__(256)
void cvt_f32_bf16(const float* __restrict__ in, ushort* __restrict__ out, int n4)
{
    int i = blockIdx.x * 256 + threadIdx.x;
    if (i >= n4) return;
    float4 v = ((const float4*)in)[i];
    union { ushort u[4]; uint2 q; } o;
    o.u[0] = (ushort)f2bs(v.x); o.u[1] = (ushort)f2bs(v.y);
    o.u[2] = (ushort)f2bs(v.z); o.u[3] = (ushort)f2bs(v.w);
    ((uint2*)out)[i] = o.q;
}

// -------- C = A * B^T ; A:[M][K], B:[N][K] row-major, k contiguous --------
// MODE 0: bf16 store. MODE 1: fp32 atomicAdd (split-K). MODE 2: fp32 store.
// A_F32: A operand is fp32 in global memory (staged fp32, cvt at frag load).
template <int MODE, int A_F32>
__global__ __launch_bounds__(256)
void gemm_bt(const void* __restrict__ Av, const bf16* __restrict__ B,
             void* __restrict__ Cv, int M, int N, int K, int kChunks,
             long sA, long sB, long sC)
{
    __shared__ __align__(16) bf16 lA[BM * BK * (A_F32 ? 2 : 1)];
    __shared__ __align__(16) bf16 lB[BN * BK];

    const int z     = blockIdx.z;
    const int batch = z / kChunks;
    const int chunk = z - batch * kChunks;
    const int kLen  = K / kChunks;
    const int k0    = chunk * kLen;

    const int m0 = blockIdx.y * BM;
    const int n0 = blockIdx.x * BN;

    const int tid  = threadIdx.x;
    const int lane = tid & 63;
    const int wave = tid >> 6;
    const int wr   = wave >> 1, wc = wave & 1;   // 2x2 wave grid, 64x64 each
    const int ml   = lane & 15;
    const int q    = lane >> 4;

    // B staging: 2 shots x 256 lanes x 16B, bf16-swizzled source columns
    const bf16* Bb = B + (size_t)batch * sB;
    const bf16* bp[2];
#pragma unroll
    for (int s = 0; s < 2; ++s) {
        int idx = s * 256 + tid;
        int row = idx >> 2, cg = idx & 3;
        bp[s] = Bb + (size_t)(n0 + row) * K + k0 + 8 * bswz(row, cg);
    }

    // A staging pointers (swizzled)
    const float* a32[4];
    const bf16*  a16[2];
    if constexpr (A_F32) {
        const float* Ab = (const float*)Av + (size_t)batch * sA;
#pragma unroll
        for (int s = 0; s < 4; ++s) {
            int idx = s * 256 + tid;
            int row = idx >> 3, cg = idx & 7;
            a32[s] = Ab + (size_t)(m0 + row) * K + k0 + 4 * fswz(row, cg);
        }
    } else {
        const bf16* Ab = (const bf16*)Av + (size_t)batch * sA;
#pragma unroll
        for (int s = 0; s < 2; ++s) {
            int idx = s * 256 + tid;
            int row = idx >> 2, cg = idx & 3;
            a16[s] = Ab + (size_t)(m0 + row) * K + k0 + 8 * bswz(row, cg);
        }
    }

    f32x4 acc[4][4] = {};

    const int nk = kLen / BK;
    for (int kt = 0; kt < nk; ++kt) {
        if constexpr (A_F32) {
            float* lAf = (float*)lA;
#pragma unroll
            for (int s = 0; s < 4; ++s) {
                g2lds16(a32[s], &lAf[(s * 256 + tid) * 4]);
                a32[s] += BK;
            }
        } else {
#pragma unroll
            for (int s = 0; s < 2; ++s) {
                g2lds16(a16[s], &lA[(s * 256 + tid) * 8]);
                a16[s] += BK;
            }
        }
#pragma unroll
        for (int s = 0; s < 2; ++s) {
            g2lds16(bp[s], &lB[(s * 256 + tid) * 8]);
            bp[s] += BK;
        }
        __syncthreads();

        short8 af[4], bfr[4];
#pragma unroll
        for (int i = 0; i < 4; ++i) {
            const int rA = wr * 64 + i * 16 + ml;
            const int rB = wc * 64 + i * 16 + ml;
            if constexpr (A_F32) {
                const float* lAf = (const float*)lA;
                // global float groups 2q, 2q+1 of row rA, at swizzled slots
                float4 x0 = *(const float4*)&lAf[rA * 32 + 4 * fswz(rA, 2 * q)];
                float4 x1 = *(const float4*)&lAf[rA * 32 + 4 * fswz(rA, 2 * q + 1)];
                af[i][0] = f2bs(x0.x); af[i][1] = f2bs(x0.y);
                af[i][2] = f2bs(x0.z); af[i][3] = f2bs(x0.w);
                af[i][4] = f2bs(x1.x); af[i][5] = f2bs(x1.y);
                af[i][6] = f2bs(x1.z); af[i][7] = f2bs(x1.w);
            } else {
                af[i] = *(const short8*)&lA[rA * 32 + 8 * bswz(rA, q)];
            }
            bfr[i] = *(const short8*)&lB[rB * 32 + 8 * bswz(rB, q)];
        }
#pragma unroll
        for (int mi = 0; mi < 4; ++mi)
#pragma unroll
            for (int ni = 0; ni < 4; ++ni)
                acc[mi][ni] = __builtin_amdgcn_mfma_f32_16x16x32_bf16(
                    af[mi], bfr[ni], acc[mi][ni], 0, 0, 0);
        __syncthreads();
    }

    // epilogue: C/D layout col=lane&15, row=(lane>>4)*4+r (m89-verified)
#pragma unroll
    for (int mi = 0; mi < 4; ++mi)
#pragma unroll
        for (int ni = 0; ni < 4; ++ni)
#pragma unroll
            for (int r = 0; r < 4; ++r) {
                int row = m0 + wr * 64 + mi * 16 + q * 4 + r;
                int col = n0 + wc * 64 + ni * 16 + ml;
                if constexpr (MODE == 1) {
                    float* Cf = (float*)Cv + (size_t)batch * sC;
                    atomicAdd(&Cf[(size_t)row * N + col], acc[mi][ni][r]);
                } else if constexpr (MODE == 0) {
                    ushort* Cb = (ushort*)Cv + (size_t)batch * sC;
                    Cb[(size_t)row * N + col] = (ushort)f2bs(acc[mi][ni][r]);
                } else {
                    float* Cf = (float*)Cv + (size_t)batch * sC;
                    Cf[(size_t)row * N + col] = acc[mi][ni][r];
                }
            }
}

// ---------------------------------------------------------------
// fp32 I/O.  O = ((X W^T) X^T) X == X * (W^T (X^T X))   [associative]
//   G  = Xt * Xt^T   (split-K=4, fp32 atomic)     Xt = bf16(X)^T
//   Mt = G * Wt^T    (bf16 store)                 Wt = bf16(W)^T
//   O  = X * Mt^T    (A fp32 on-the-fly cvt, fp32 store)
// d_out (32 MiB) doubles as scratch until step 7 overwrites it:
//   Xt bf16 @0 (16M) | Gf f32 @16M (8M) | G bf16 @24M (4M) | Wt @28M (2M)
// ws: Mt bf16 @0 (4 MiB) — only ws use.
// ---------------------------------------------------------------
extern "C" void kernel_launch(void* const* d_in, const int* in_sizes, int n_in,
                              void* d_out, int out_size, void* d_ws, size_t ws_size,
                              hipStream_t stream)
{
    const int B = 2, N = 4096, D = 1024;
    const float* X = (const float*)d_in[0];   // [B][N][D] fp32
    const float* W = (const float*)d_in[1];   // [D][D]    fp32
    float* out = (float*)d_out;               // [B][N][D] fp32

    char* ob = (char*)d_out;
    ushort* Xt = (ushort*)ob;                  // [B][D][N] bf16, 16 MiB
    float*  Gf = (float*)(ob + (16ll << 20));  // [B][D][D] fp32,  8 MiB
    ushort* G  = (ushort*)(ob + (24ll << 20)); // [B][D][D] bf16,  4 MiB
    ushort* Wt = (ushort*)(ob + (28ll << 20)); // [D][D]    bf16,  2 MiB
    ushort* Mt = (ushort*)d_ws;                // [B][D][D] bf16,  4 MiB

    // 1) Xt[b] = bf16(X[b])^T
    transpose_cvt<<<dim3(D / 64, N / 64, B), 256, 0, stream>>>(
        X, Xt, N, D, (long)N * D, (long)D * N);
    // 2) Wt = bf16(W)^T
    transpose_cvt<<<dim3(D / 64, D / 64, 1), 256, 0, stream>>>(
        W, Wt, D, D, 0, 0);
    // 3) zero split-K accumulator
    (void)hipMemsetAsync(Gf, 0, (size_t)B * D * D * sizeof(float), stream);
    // 4) Gf[b] += Xt[b] * Xt[b]^T   (M=N=D, K=4096, split-K 4)
    gemm_bt<1, 0><<<dim3(D / BN, D / BM, B * 4), 256, 0, stream>>>(
        (const void*)Xt, (const bf16*)Xt, Gf, D, D, N, 4,
        (long)D * N, (long)D * N, (long)D * D);
    // 5) G = bf16(Gf)
    cvt_f32_bf16<<<dim3((B * D * D / 4 + 255) / 256), 256, 0, stream>>>(
        Gf, G, B * D * D / 4);
    // 6) Mt[b] = G[b] * Wt^T   (M=N=K=D)
    gemm_bt<0, 0><<<dim3(D / BN, D / BM, B), 256, 0, stream>>>(
        (const void*)G, (const bf16*)Wt, Mt, D, D, D, 1,
        (long)D * D, 0, (long)D * D);
    // 7) O[b] = X[b] * Mt[b]^T  (M=4096, N=D, K=D; A fp32; overwrites d_out)
    gemm_bt<2, 1><<<dim3(D / BN, N / BM, B), 256, 0, stream>>>(
        (const void*)X, (const bf16*)Mt, out, N, D, D, 1,
        (long)N * D, (long)D * D, (long)N * D);
}

// Round 6
// 196.581 us; speedup vs baseline: 1.4160x; 1.0460x over previous
//
#include <hip/hip_runtime.h>
#include <hip/hip_bf16.h>
#include <stdint.h>

using bf16 = __hip_bfloat16;
typedef __attribute__((ext_vector_type(8))) short short8;
typedef __attribute__((ext_vector_type(4))) float f32x4;

#define BM 128
#define BK 32

// -------- async global->LDS, 16B per lane (m97 pattern) --------
__device__ __forceinline__ void g2lds16(const void* g, void* l) {
    __builtin_amdgcn_global_load_lds(
        (const __attribute__((address_space(1))) void*)g,
        (__attribute__((address_space(3))) void*)l,
        16, 0, 0);
}

__device__ __forceinline__ short f2bs(float x) {
    union { bf16 h; short s; } u;
    u.h = __float2bfloat16(x);
    return u.s;
}

// ---- LDS XOR swizzles (conflict-free fragment reads; round-4 fix) ----
// bf16 tile [rows][32 bf16] = 4 groups/row of 8 bf16 (16B). s=(row>>1)&3.
__device__ __forceinline__ int bswz(int row, int cg) { return cg ^ ((row >> 1) & 3); }
// fp32 tile [rows][32 f32] = 8 groups/row of 4 f32 (16B). s=row&7.
__device__ __forceinline__ int fswz(int row, int cg) { return cg ^ (row & 7); }

// ---- fp32 -> bf16 64x64 tile transpose (+ optional row-major bf16 copy) ----
__global__ __launch_bounds__(256)
void transpose_cvt(const float* __restrict__ src, ushort* __restrict__ dstT,
                   ushort* __restrict__ dstN,
                   int R, int C, long sstride, long dstrideT, long dstrideN)
{
    __shared__ __align__(16) ushort t[64][72];
    const float* s = src + (size_t)blockIdx.z * sstride;
    ushort*      dT = dstT + (size_t)blockIdx.z * dstrideT;
    const int r0 = blockIdx.y * 64, c0 = blockIdx.x * 64;
    const int tid = threadIdx.x;
#pragma unroll
    for (int ii = 0; ii < 4; ++ii) {
        int idx = ii * 256 + tid;
        int r = idx >> 4, c4 = (idx & 15) * 4;
        float4 v = *(const float4*)&s[(size_t)(r0 + r) * C + c0 + c4];
        union { ushort u[4]; uint2 q; } o;
        o.u[0] = (ushort)f2bs(v.x); o.u[1] = (ushort)f2bs(v.y);
        o.u[2] = (ushort)f2bs(v.z); o.u[3] = (ushort)f2bs(v.w);
        *(uint2*)&t[r][c4] = o.q;
        if (dstN) {
            ushort* dN = dstN + (size_t)blockIdx.z * dstrideN;
            *(uint2*)&dN[(size_t)(r0 + r) * C + c0 + c4] = o.q;
        }
    }
    __syncthreads();
#pragma unroll
    for (int ii = 0; ii < 2; ++ii) {
        int idx = ii * 256 + tid;
        int c = idx >> 3, r8 = (idx & 7) * 8;
        union { ushort u[8]; uint4 v; } tmp;
#pragma unroll
        for (int j = 0; j < 8; ++j) tmp.u[j] = t[r8 + j][c];
        *(uint4*)&dT[(size_t)(c0 + c) * R + r0 + r8] = tmp.v;
    }
}

// -------- fp32 -> bf16 flat convert (4 elems/thread) --------
__global__ __launch_bounds__(256)
void cvt_f32_bf16(const float* __restrict__ in, ushort* __restrict__ out, int n4)
{
    int i = blockIdx.x * 256 + threadIdx.x;
    if (i >= n4) return;
    float4 v = ((const float4*)in)[i];
    union { ushort u[4]; uint2 q; } o;
    o.u[0] = (ushort)f2bs(v.x); o.u[1] = (ushort)f2bs(v.y);
    o.u[2] = (ushort)f2bs(v.z); o.u[3] = (ushort)f2bs(v.w);
    ((uint2*)out)[i] = o.q;
}

// -------- C = A * B^T ; A:[M][K], B:[N][K] row-major, k contiguous --------
// MODE 0: bf16 store. MODE 1: fp32 atomicAdd (split-K). MODE 2: fp32 store.
// A_F32: A operand fp32 in global (staged fp32, cvt at frag load).
// NFRAG: n-fragments (16-wide) per wave; BN = 32*NFRAG. Waves 2x2,
//        wave tile 64 x (16*NFRAG).
template <int MODE, int A_F32, int NFRAG>
__global__ __launch_bounds__(256)
void gemm_bt(const void* __restrict__ Av, const bf16* __restrict__ B,
             void* __restrict__ Cv, int M, int N, int K, int kChunks,
             long sA, long sB, long sC)
{
    constexpr int BN  = 32 * NFRAG;
    constexpr int BSH = BN / 64;            // B staging shots (256x16B each)
    __shared__ __align__(16) bf16 lA[BM * BK * (A_F32 ? 2 : 1)];
    __shared__ __align__(16) bf16 lB[BN * BK];

    const int z     = blockIdx.z;
    const int batch = z / kChunks;
    const int chunk = z - batch * kChunks;
    const int kLen  = K / kChunks;
    const int k0    = chunk * kLen;

    const int m0 = blockIdx.y * BM;
    const int n0 = blockIdx.x * BN;

    const int tid  = threadIdx.x;
    const int lane = tid & 63;
    const int wave = tid >> 6;
    const int wr   = wave >> 1, wc = wave & 1;
    const int ml   = lane & 15;
    const int q    = lane >> 4;

    // B staging pointers (swizzled)
    const bf16* Bb = B + (size_t)batch * sB;
    const bf16* bp[BSH];
#pragma unroll
    for (int s = 0; s < BSH; ++s) {
        int idx = s * 256 + tid;
        int row = idx >> 2, cg = idx & 3;
        bp[s] = Bb + (size_t)(n0 + row) * K + k0 + 8 * bswz(row, cg);
    }

    // A staging pointers (swizzled)
    const float* a32[4];
    const bf16*  a16[2];
    if constexpr (A_F32) {
        const float* Ab = (const float*)Av + (size_t)batch * sA;
#pragma unroll
        for (int s = 0; s < 4; ++s) {
            int idx = s * 256 + tid;
            int row = idx >> 3, cg = idx & 7;
            a32[s] = Ab + (size_t)(m0 + row) * K + k0 + 4 * fswz(row, cg);
        }
    } else {
        const bf16* Ab = (const bf16*)Av + (size_t)batch * sA;
#pragma unroll
        for (int s = 0; s < 2; ++s) {
            int idx = s * 256 + tid;
            int row = idx >> 2, cg = idx & 3;
            a16[s] = Ab + (size_t)(m0 + row) * K + k0 + 8 * bswz(row, cg);
        }
    }

    f32x4 acc[4][NFRAG] = {};

    const int nk = kLen / BK;
    for (int kt = 0; kt < nk; ++kt) {
        if constexpr (A_F32) {
            float* lAf = (float*)lA;
#pragma unroll
            for (int s = 0; s < 4; ++s) {
                g2lds16(a32[s], &lAf[(s * 256 + tid) * 4]);
                a32[s] += BK;
            }
        } else {
#pragma unroll
            for (int s = 0; s < 2; ++s) {
                g2lds16(a16[s], &lA[(s * 256 + tid) * 8]);
                a16[s] += BK;
            }
        }
#pragma unroll
        for (int s = 0; s < BSH; ++s) {
            g2lds16(bp[s], &lB[(s * 256 + tid) * 8]);
            bp[s] += BK;
        }
        __syncthreads();

        short8 af[4], bfr[NFRAG];
#pragma unroll
        for (int i = 0; i < 4; ++i) {
            const int rA = wr * 64 + i * 16 + ml;
            if constexpr (A_F32) {
                const float* lAf = (const float*)lA;
                float4 x0 = *(const float4*)&lAf[rA * 32 + 4 * fswz(rA, 2 * q)];
                float4 x1 = *(const float4*)&lAf[rA * 32 + 4 * fswz(rA, 2 * q + 1)];
                af[i][0] = f2bs(x0.x); af[i][1] = f2bs(x0.y);
                af[i][2] = f2bs(x0.z); af[i][3] = f2bs(x0.w);
                af[i][4] = f2bs(x1.x); af[i][5] = f2bs(x1.y);
                af[i][6] = f2bs(x1.z); af[i][7] = f2bs(x1.w);
            } else {
                af[i] = *(const short8*)&lA[rA * 32 + 8 * bswz(rA, q)];
            }
        }
#pragma unroll
        for (int j = 0; j < NFRAG; ++j) {
            const int rB = wc * (16 * NFRAG) + j * 16 + ml;
            bfr[j] = *(const short8*)&lB[rB * 32 + 8 * bswz(rB, q)];
        }
#pragma unroll
        for (int mi = 0; mi < 4; ++mi)
#pragma unroll
            for (int nj = 0; nj < NFRAG; ++nj)
                acc[mi][nj] = __builtin_amdgcn_mfma_f32_16x16x32_bf16(
                    af[mi], bfr[nj], acc[mi][nj], 0, 0, 0);
        __syncthreads();
    }

    // epilogue: C/D layout col=lane&15, row=(lane>>4)*4+r (m89-verified)
#pragma unroll
    for (int mi = 0; mi < 4; ++mi)
#pragma unroll
        for (int nj = 0; nj < NFRAG; ++nj)
#pragma unroll
            for (int r = 0; r < 4; ++r) {
                int row = m0 + wr * 64 + mi * 16 + q * 4 + r;
                int col = n0 + wc * (16 * NFRAG) + nj * 16 + ml;
                if constexpr (MODE == 1) {
                    float* Cf = (float*)Cv + (size_t)batch * sC;
                    atomicAdd(&Cf[(size_t)row * N + col], acc[mi][nj][r]);
                } else if constexpr (MODE == 0) {
                    ushort* Cb = (ushort*)Cv + (size_t)batch * sC;
                    Cb[(size_t)row * N + col] = (ushort)f2bs(acc[mi][nj][r]);
                } else {
                    float* Cf = (float*)Cv + (size_t)batch * sC;
                    Cf[(size_t)row * N + col] = acc[mi][nj][r];
                }
            }
}

// ---------------------------------------------------------------
// fp32 I/O.  O = ((X W^T) X^T) X == X * (W^T (X^T X))   [associative]
//   G  = Xt * Xt^T   (split-K=4, fp32 atomic)     Xt = bf16(X)^T
//   Mt = G * Wt^T    (bf16 store)                 Wt = bf16(W)^T
//   O  = X * Mt^T    (fp32 store; A = Xb bf16 if ws fits, else X fp32)
// d_out scratch (dead before step 7 overwrites):
//   Xt bf16 @0 (16M) | Gf f32 @16M (8M) | G bf16 @24M (4M) | Wt @28M (2M)
// ws: [Xb bf16 16M if ws_size>=20M] + Mt bf16 4M.
// ---------------------------------------------------------------
extern "C" void kernel_launch(void* const* d_in, const int* in_sizes, int n_in,
                              void* d_out, int out_size, void* d_ws, size_t ws_size,
                              hipStream_t stream)
{
    const int B = 2, N = 4096, D = 1024;
    const float* X = (const float*)d_in[0];   // [B][N][D] fp32
    const float* W = (const float*)d_in[1];   // [D][D]    fp32
    float* out = (float*)d_out;               // [B][N][D] fp32

    char* ob = (char*)d_out;
    char* ws = (char*)d_ws;
    ushort* Xt = (ushort*)ob;                  // [B][D][N] bf16, 16 MiB
    float*  Gf = (float*)(ob + (16ll << 20));  // [B][D][D] fp32,  8 MiB
    ushort* G  = (ushort*)(ob + (24ll << 20)); // [B][D][D] bf16,  4 MiB
    ushort* Wt = (ushort*)(ob + (28ll << 20)); // [D][D]    bf16,  2 MiB

    const bool bigws = ws_size >= (20ull << 20);
    ushort* Xb = bigws ? (ushort*)ws : nullptr;             // [B][N][D] bf16, 16 MiB
    ushort* Mt = (ushort*)(ws + (bigws ? (16ll << 20) : 0)); // [B][D][D] bf16, 4 MiB

    // 1) Xt[b] = bf16(X[b])^T  (+ Xb = bf16(X) row-major when ws allows)
    transpose_cvt<<<dim3(D / 64, N / 64, B), 256, 0, stream>>>(
        X, Xt, Xb, N, D, (long)N * D, (long)D * N, (long)N * D);
    // 2) Wt = bf16(W)^T
    transpose_cvt<<<dim3(D / 64, D / 64, 1), 256, 0, stream>>>(
        W, Wt, nullptr, D, D, 0, 0, 0);
    // 3) zero split-K accumulator
    (void)hipMemsetAsync(Gf, 0, (size_t)B * D * D * sizeof(float), stream);
    // 4) Gf[b] += Xt[b] * Xt[b]^T   (M=N=D, K=4096, split-K 4, BN=64)
    gemm_bt<1, 0, 2><<<dim3(D / 64, D / BM, B * 4), 256, 0, stream>>>(
        (const void*)Xt, (const bf16*)Xt, Gf, D, D, N, 4,
        (long)D * N, (long)D * N, (long)D * D);
    // 5) G = bf16(Gf)
    cvt_f32_bf16<<<dim3((B * D * D / 4 + 255) / 256), 256, 0, stream>>>(
        Gf, G, B * D * D / 4);
    // 6) Mt[b] = G[b] * Wt^T   (M=N=K=D, BN=64)
    gemm_bt<0, 0, 2><<<dim3(D / 64, D / BM, B), 256, 0, stream>>>(
        (const void*)G, (const bf16*)Wt, Mt, D, D, D, 1,
        (long)D * D, 0, (long)D * D);
    // 7) O[b] = X[b] * Mt[b]^T  (M=4096, N=D, K=D, BN=64; overwrites d_out)
    if (bigws) {
        gemm_bt<2, 0, 2><<<dim3(D / 64, N / BM, B), 256, 0, stream>>>(
            (const void*)Xb, (const bf16*)Mt, out, N, D, D, 1,
            (long)N * D, (long)D * D, (long)N * D);
    } else {
        gemm_bt<2, 1, 2><<<dim3(D / 64, N / BM, B), 256, 0, stream>>>(
            (const void*)X, (const bf16*)Mt, out, N, D, D, 1,
            (long)N * D, (long)D * D, (long)N * D);
    }
}